// Round 1
// baseline (3084.396 us; speedup 1.0000x reference)
//
#include <hip/hip_runtime.h>
#include <math.h>

#define HDIM 128

// ---------- 1. degree count (edges only; self-loop added in dinv) ----------
__global__ void deg_kernel(const int* __restrict__ dst, int E, float* __restrict__ deg) {
    int e = blockIdx.x * blockDim.x + threadIdx.x;
    if (e < E) atomicAdd(&deg[dst[e]], 1.0f);
}

// ---------- 2. dinv = 1/sqrt(deg + 1)  (in-place over deg) ----------
__global__ void dinv_kernel(float* __restrict__ deg, int n) {
    int i = blockIdx.x * blockDim.x + threadIdx.x;
    if (i < n) {
        float d = deg[i] + 1.0f;   // + self loop
        deg[i] = 1.0f / sqrtf(d);
    }
}

// ---------- 3. g[i][j] = (sum_k x[i][k] * W[j][k]) * dinv[i] ----------
// Block = 256 threads. Threads 0..127 handle rows row0..row0+3 (rset 0),
// threads 128..255 handle rows row0+4..row0+7 (rset 1). Each thread owns
// output column j = t & 127 for its 4 rows. x rows staged in LDS (broadcast
// reads); W rows read from global (64 KB, L1/L2 resident, sequential per lane).
__global__ __launch_bounds__(256) void gemm_kernel(
    const float* __restrict__ x, const float* __restrict__ W,
    const float* __restrict__ dinv, float* __restrict__ g, int n) {
    __shared__ float xs[8][HDIM];
    const int t = threadIdx.x;
    const int j = t & 127;
    const int rset = t >> 7;          // 0 or 1
    const int ngroups = (n + 7) >> 3;

    for (int grp = blockIdx.x; grp < ngroups; grp += gridDim.x) {
        const int row0 = grp << 3;
        // cooperative load of 8 x-rows (1024 floats): 1 float4 per thread
        {
            int r = t >> 5;
            int col4 = (t & 31) << 2;
            int row = row0 + r;
            float4 v = make_float4(0.f, 0.f, 0.f, 0.f);
            if (row < n) v = *(const float4*)(x + (size_t)row * HDIM + col4);
            *(float4*)(&xs[r][col4]) = v;
        }
        __syncthreads();

        float acc0 = 0.f, acc1 = 0.f, acc2 = 0.f, acc3 = 0.f;
        const float4* __restrict__ Wrow = (const float4*)(W + (size_t)j * HDIM);
        const int rb = rset << 2;
        #pragma unroll 8
        for (int k4 = 0; k4 < HDIM / 4; ++k4) {
            float4 w = Wrow[k4];
            float4 a = *(const float4*)(&xs[rb + 0][k4 << 2]);
            float4 b = *(const float4*)(&xs[rb + 1][k4 << 2]);
            float4 c = *(const float4*)(&xs[rb + 2][k4 << 2]);
            float4 d = *(const float4*)(&xs[rb + 3][k4 << 2]);
            acc0 += w.x * a.x + w.y * a.y + w.z * a.z + w.w * a.w;
            acc1 += w.x * b.x + w.y * b.y + w.z * b.z + w.w * b.w;
            acc2 += w.x * c.x + w.y * c.y + w.z * c.z + w.w * c.w;
            acc3 += w.x * d.x + w.y * d.y + w.z * d.z + w.w * d.w;
        }
        const int r0 = row0 + rb;
        if (r0 + 0 < n) g[(size_t)(r0 + 0) * HDIM + j] = acc0 * dinv[r0 + 0];
        if (r0 + 1 < n) g[(size_t)(r0 + 1) * HDIM + j] = acc1 * dinv[r0 + 1];
        if (r0 + 2 < n) g[(size_t)(r0 + 2) * HDIM + j] = acc2 * dinv[r0 + 2];
        if (r0 + 3 < n) g[(size_t)(r0 + 3) * HDIM + j] = acc3 * dinv[r0 + 3];
        __syncthreads();
    }
}

// ---------- 4. scatter: acc[dst] += g[src]  (un-normalized, atomics) ----------
// 32 threads per edge, 1 float4 (4 atomics) each.
__global__ __launch_bounds__(256) void scatter_kernel(
    const int* __restrict__ ei, int E,
    const float* __restrict__ g, float* __restrict__ out) {
    long long idx = (long long)blockIdx.x * blockDim.x + threadIdx.x;
    long long total = (long long)E * 32;
    if (idx >= total) return;
    int e = (int)(idx >> 5);
    int c = (int)(idx & 31);
    int s = ei[e];          // edge_index[0][e]
    int d = ei[E + e];      // edge_index[1][e]
    float4 v = *(const float4*)(g + (size_t)s * HDIM + (c << 2));
    float* o = out + (size_t)d * HDIM + (c << 2);
    atomicAdd(o + 0, v.x);
    atomicAdd(o + 1, v.y);
    atomicAdd(o + 2, v.z);
    atomicAdd(o + 3, v.w);
}

// ---------- 5. epilogue: out = prelu(dinv[i]*(acc + g) + b) ----------
__global__ __launch_bounds__(256) void final_kernel(
    float* __restrict__ out, const float* __restrict__ g,
    const float* __restrict__ dinv, const float* __restrict__ bias,
    const float* __restrict__ prelu_a, int n) {
    int idx = blockIdx.x * blockDim.x + threadIdx.x;   // one float4 each
    int total = n * (HDIM / 4);
    if (idx >= total) return;
    int i = idx >> 5;
    int c = idx & 31;
    float s = dinv[i];
    float a = prelu_a[0];
    float4 acc = *(float4*)(out + (size_t)idx * 4);
    float4 gg  = *(const float4*)(g + (size_t)idx * 4);
    float4 bb  = *(const float4*)(bias + (c << 2));
    float vx = s * (acc.x + gg.x) + bb.x;
    float vy = s * (acc.y + gg.y) + bb.y;
    float vz = s * (acc.z + gg.z) + bb.z;
    float vw = s * (acc.w + gg.w) + bb.w;
    vx = vx >= 0.f ? vx : a * vx;
    vy = vy >= 0.f ? vy : a * vy;
    vz = vz >= 0.f ? vz : a * vz;
    vw = vw >= 0.f ? vw : a * vw;
    *(float4*)(out + (size_t)idx * 4) = make_float4(vx, vy, vz, vw);
}

extern "C" void kernel_launch(void* const* d_in, const int* in_sizes, int n_in,
                              void* d_out, int out_size, void* d_ws, size_t ws_size,
                              hipStream_t stream) {
    const float* x   = (const float*)d_in[0];
    const int*   ei  = (const int*)d_in[1];    // edge_index, shape (2, E), int32
    const float* W   = (const float*)d_in[2];
    const float* b   = (const float*)d_in[3];
    const float* pa  = (const float*)d_in[4];

    const int n = in_sizes[0] / HDIM;          // 100000
    const int E = in_sizes[1] / 2;             // 1600000

    float* out = (float*)d_out;
    // workspace layout: g [n*128 floats] | deg/dinv [n floats]
    float* g   = (float*)d_ws;
    float* deg = g + (size_t)n * HDIM;

    hipMemsetAsync(deg, 0, (size_t)n * sizeof(float), stream);
    hipMemsetAsync(out, 0, (size_t)n * HDIM * sizeof(float), stream);

    deg_kernel<<<(E + 255) / 256, 256, 0, stream>>>(ei + E, E, deg);
    dinv_kernel<<<(n + 255) / 256, 256, 0, stream>>>(deg, n);
    gemm_kernel<<<1024, 256, 0, stream>>>(x, W, deg, g, n);
    long long sthreads = (long long)E * 32;
    scatter_kernel<<<(int)((sthreads + 255) / 256), 256, 0, stream>>>(ei, E, g, out);
    final_kernel<<<(n * (HDIM / 4) + 255) / 256, 256, 0, stream>>>(out, g, deg, b, pa, n);
}

// Round 2
// 810.738 us; speedup vs baseline: 3.8044x; 3.8044x over previous
//
#include <hip/hip_runtime.h>
#include <math.h>

#define HDIM 128

// ---------- 1. in-degree histogram (dst occurrences, excl. self-loop) ----------
__global__ void cnt_kernel(const int* __restrict__ dst, int E, int* __restrict__ cnt) {
    int e = blockIdx.x * blockDim.x + threadIdx.x;
    if (e < E) atomicAdd(&cnt[dst[e]], 1);
}

// ---------- 2. dinv = 1/sqrt(cnt + 1) ----------
__global__ void dinv_kernel(const int* __restrict__ cnt, float* __restrict__ dinv, int n) {
    int i = blockIdx.x * blockDim.x + threadIdx.x;
    if (i < n) dinv[i] = rsqrtf((float)cnt[i] + 1.0f);
}

// ---------- 3. exclusive prefix scan over cnt -> row_ptr (+ running copy ptr) ----------
// Single block, 1024 threads, chunked serial + Hillis-Steele block scan.
__global__ __launch_bounds__(1024) void scan_kernel(
    const int* __restrict__ cnt, int* __restrict__ row_ptr,
    int* __restrict__ ptr, int n) {
    __shared__ int sums[1024];
    const int t = threadIdx.x;
    const int chunk = (n + 1023) / 1024;
    const int start = t * chunk;
    const int end = min(start + chunk, n);
    int s = 0;
    for (int i = start; i < end; ++i) s += cnt[i];
    sums[t] = s;
    __syncthreads();
    for (int off = 1; off < 1024; off <<= 1) {
        int v = (t >= off) ? sums[t - off] : 0;
        __syncthreads();
        sums[t] += v;
        __syncthreads();
    }
    int run = (t == 0) ? 0 : sums[t - 1];
    for (int i = start; i < end; ++i) {
        row_ptr[i] = run;
        ptr[i] = run;
        run += cnt[i];
    }
    if (t == 1023) row_ptr[n] = sums[1023];
}

// ---------- 4. CSR fill: col[ptr[dst]++] = src ----------
__global__ void fill_kernel(const int* __restrict__ ei, int E,
                            int* __restrict__ ptr, int* __restrict__ col) {
    int e = blockIdx.x * blockDim.x + threadIdx.x;
    if (e >= E) return;
    int s = ei[e];        // src
    int d = ei[E + e];    // dst
    int pos = atomicAdd(&ptr[d], 1);
    col[pos] = s;
}

// ---------- 5. g[i][j] = (sum_k x[i][k] * W[j][k]) * dinv[i] ----------
__global__ __launch_bounds__(256) void gemm_kernel(
    const float* __restrict__ x, const float* __restrict__ W,
    const float* __restrict__ dinv, float* __restrict__ g, int n) {
    __shared__ float xs[8][HDIM];
    const int t = threadIdx.x;
    const int j = t & 127;
    const int rset = t >> 7;
    const int ngroups = (n + 7) >> 3;

    for (int grp = blockIdx.x; grp < ngroups; grp += gridDim.x) {
        const int row0 = grp << 3;
        {
            int r = t >> 5;
            int col4 = (t & 31) << 2;
            int row = row0 + r;
            float4 v = make_float4(0.f, 0.f, 0.f, 0.f);
            if (row < n) v = *(const float4*)(x + (size_t)row * HDIM + col4);
            *(float4*)(&xs[r][col4]) = v;
        }
        __syncthreads();

        float acc0 = 0.f, acc1 = 0.f, acc2 = 0.f, acc3 = 0.f;
        const float4* __restrict__ Wrow = (const float4*)(W + (size_t)j * HDIM);
        const int rb = rset << 2;
        #pragma unroll 8
        for (int k4 = 0; k4 < HDIM / 4; ++k4) {
            float4 w = Wrow[k4];
            float4 a = *(const float4*)(&xs[rb + 0][k4 << 2]);
            float4 b = *(const float4*)(&xs[rb + 1][k4 << 2]);
            float4 c = *(const float4*)(&xs[rb + 2][k4 << 2]);
            float4 d = *(const float4*)(&xs[rb + 3][k4 << 2]);
            acc0 += w.x * a.x + w.y * a.y + w.z * a.z + w.w * a.w;
            acc1 += w.x * b.x + w.y * b.y + w.z * b.z + w.w * b.w;
            acc2 += w.x * c.x + w.y * c.y + w.z * c.z + w.w * c.w;
            acc3 += w.x * d.x + w.y * d.y + w.z * d.z + w.w * d.w;
        }
        const int r0 = row0 + rb;
        if (r0 + 0 < n) g[(size_t)(r0 + 0) * HDIM + j] = acc0 * dinv[r0 + 0];
        if (r0 + 1 < n) g[(size_t)(r0 + 1) * HDIM + j] = acc1 * dinv[r0 + 1];
        if (r0 + 2 < n) g[(size_t)(r0 + 2) * HDIM + j] = acc2 * dinv[r0 + 2];
        if (r0 + 3 < n) g[(size_t)(r0 + 3) * HDIM + j] = acc3 * dinv[r0 + 3];
        __syncthreads();
    }
}

// ---------- 6. pull gather + fused epilogue ----------
// One 64-lane wave per node; each lane owns 2 consecutive floats (float2).
// acc = sum over in-edges of g[src]; out = prelu(dinv*(acc + g[self]) + b).
__global__ __launch_bounds__(256) void gather_kernel(
    const int* __restrict__ row_ptr, const int* __restrict__ col,
    const float* __restrict__ g, const float* __restrict__ dinv,
    const float* __restrict__ bias, const float* __restrict__ prelu_a,
    float* __restrict__ out, int n) {
    const int wave = threadIdx.x >> 6;
    const int lane = threadIdx.x & 63;
    const int i = blockIdx.x * 4 + wave;
    if (i >= n) return;

    const int beg = row_ptr[i];
    const int end = row_ptr[i + 1];
    const float2* __restrict__ gp = (const float2*)g;

    float2 a0 = {0.f, 0.f}, a1 = {0.f, 0.f}, a2 = {0.f, 0.f}, a3 = {0.f, 0.f};
    int e = beg;
    for (; e + 4 <= end; e += 4) {
        int s0 = col[e], s1 = col[e + 1], s2 = col[e + 2], s3 = col[e + 3];
        float2 v0 = gp[(size_t)s0 * 64 + lane];
        float2 v1 = gp[(size_t)s1 * 64 + lane];
        float2 v2 = gp[(size_t)s2 * 64 + lane];
        float2 v3 = gp[(size_t)s3 * 64 + lane];
        a0.x += v0.x; a0.y += v0.y;
        a1.x += v1.x; a1.y += v1.y;
        a2.x += v2.x; a2.y += v2.y;
        a3.x += v3.x; a3.y += v3.y;
    }
    for (; e < end; ++e) {
        int s = col[e];
        float2 v = gp[(size_t)s * 64 + lane];
        a0.x += v.x; a0.y += v.y;
    }
    float accx = (a0.x + a1.x) + (a2.x + a3.x);
    float accy = (a0.y + a1.y) + (a2.y + a3.y);

    float2 self = gp[(size_t)i * 64 + lane];
    float di = dinv[i];
    float2 bb = *(const float2*)(bias + lane * 2);
    float aa = prelu_a[0];

    float vx = di * (accx + self.x) + bb.x;
    float vy = di * (accy + self.y) + bb.y;
    vx = vx >= 0.f ? vx : aa * vx;
    vy = vy >= 0.f ? vy : aa * vy;
    *(float2*)(out + (size_t)i * HDIM + lane * 2) = make_float2(vx, vy);
}

extern "C" void kernel_launch(void* const* d_in, const int* in_sizes, int n_in,
                              void* d_out, int out_size, void* d_ws, size_t ws_size,
                              hipStream_t stream) {
    const float* x  = (const float*)d_in[0];
    const int*   ei = (const int*)d_in[1];   // edge_index (2, E), int32
    const float* W  = (const float*)d_in[2];
    const float* b  = (const float*)d_in[3];
    const float* pa = (const float*)d_in[4];

    const int n = in_sizes[0] / HDIM;        // 100000
    const int E = in_sizes[1] / 2;           // 1600000

    float* out = (float*)d_out;

    // workspace layout:
    //   g       : n*128 floats
    //   dinv    : n floats
    //   cnt     : n ints
    //   row_ptr : n+1 ints
    //   ptr     : n ints
    //   col     : E ints
    float* g       = (float*)d_ws;
    float* dinv    = g + (size_t)n * HDIM;
    int*   cnt     = (int*)(dinv + n);
    int*   row_ptr = cnt + n;
    int*   ptr     = row_ptr + (n + 1);
    int*   col     = ptr + n;

    hipMemsetAsync(cnt, 0, (size_t)n * sizeof(int), stream);

    cnt_kernel<<<(E + 255) / 256, 256, 0, stream>>>(ei + E, E, cnt);
    dinv_kernel<<<(n + 255) / 256, 256, 0, stream>>>(cnt, dinv, n);
    scan_kernel<<<1, 1024, 0, stream>>>(cnt, row_ptr, ptr, n);
    fill_kernel<<<(E + 255) / 256, 256, 0, stream>>>(ei, E, ptr, col);
    gemm_kernel<<<1024, 256, 0, stream>>>(x, W, dinv, g, n);
    gather_kernel<<<(n + 3) / 4, 256, 0, stream>>>(row_ptr, col, g, dinv, b, pa, out, n);
}

// Round 3
// 604.474 us; speedup vs baseline: 5.1026x; 1.3412x over previous
//
#include <hip/hip_runtime.h>
#include <math.h>

#define HDIM 128

// ---------- 1. in-degree histogram (dst occurrences, excl. self-loop) ----------
__global__ void cnt_kernel(const int* __restrict__ dst, int E, int* __restrict__ cnt) {
    int e = blockIdx.x * blockDim.x + threadIdx.x;
    if (e < E) atomicAdd(&cnt[dst[e]], 1);
}

// ---------- 2. dinv = 1/sqrt(cnt + 1) ----------
__global__ void dinv_kernel(const int* __restrict__ cnt, float* __restrict__ dinv, int n) {
    int i = blockIdx.x * blockDim.x + threadIdx.x;
    if (i < n) dinv[i] = rsqrtf((float)cnt[i] + 1.0f);
}

// ---------- 3a. per-block sums ----------
__global__ __launch_bounds__(1024) void scan1_kernel(
    const int* __restrict__ cnt, int* __restrict__ bsum, int n) {
    __shared__ int s[1024];
    const int t = threadIdx.x;
    int i = blockIdx.x * 1024 + t;
    s[t] = (i < n) ? cnt[i] : 0;
    __syncthreads();
    for (int off = 512; off > 0; off >>= 1) {
        if (t < off) s[t] += s[t + off];
        __syncthreads();
    }
    if (t == 0) bsum[blockIdx.x] = s[0];
}

// ---------- 3b. exclusive scan of block sums (nb <= 1024, single block) ----------
__global__ __launch_bounds__(1024) void scan2_kernel(int* __restrict__ bsum, int nb) {
    __shared__ int s[1024];
    const int t = threadIdx.x;
    int v = (t < nb) ? bsum[t] : 0;
    s[t] = v;
    __syncthreads();
    for (int off = 1; off < 1024; off <<= 1) {
        int u = (t >= off) ? s[t - off] : 0;
        __syncthreads();
        s[t] += u;
        __syncthreads();
    }
    if (t < nb) bsum[t] = s[t] - v;   // exclusive
}

// ---------- 3c. per-block exclusive scan + block offset -> row_ptr, ptr ----------
__global__ __launch_bounds__(1024) void scan3_kernel(
    const int* __restrict__ cnt, const int* __restrict__ bsum,
    int* __restrict__ row_ptr, int* __restrict__ ptr, int n) {
    __shared__ int s[1024];
    const int t = threadIdx.x;
    int i = blockIdx.x * 1024 + t;
    int v = (i < n) ? cnt[i] : 0;
    s[t] = v;
    __syncthreads();
    for (int off = 1; off < 1024; off <<= 1) {
        int u = (t >= off) ? s[t - off] : 0;
        __syncthreads();
        s[t] += u;
        __syncthreads();
    }
    int excl = s[t] - v + bsum[blockIdx.x];
    if (i < n) {
        row_ptr[i] = excl;
        ptr[i] = excl;
        if (i == n - 1) row_ptr[n] = excl + v;
    }
}

// ---------- 4. CSR fill: col[ptr[dst]++] = src ----------
__global__ void fill_kernel(const int* __restrict__ ei, int E,
                            int* __restrict__ ptr, int* __restrict__ col) {
    int e = blockIdx.x * blockDim.x + threadIdx.x;
    if (e >= E) return;
    int s = ei[e];        // src
    int d = ei[E + e];    // dst
    int pos = atomicAdd(&ptr[d], 1);
    col[pos] = s;
}

// ---------- 5. g[i][j] = (sum_k x[i][k] * W[j][k]) * dinv[i] ----------
__global__ __launch_bounds__(256) void gemm_kernel(
    const float* __restrict__ x, const float* __restrict__ W,
    const float* __restrict__ dinv, float* __restrict__ g, int n) {
    __shared__ float xs[8][HDIM];
    const int t = threadIdx.x;
    const int j = t & 127;
    const int rset = t >> 7;
    const int ngroups = (n + 7) >> 3;

    for (int grp = blockIdx.x; grp < ngroups; grp += gridDim.x) {
        const int row0 = grp << 3;
        {
            int r = t >> 5;
            int col4 = (t & 31) << 2;
            int row = row0 + r;
            float4 v = make_float4(0.f, 0.f, 0.f, 0.f);
            if (row < n) v = *(const float4*)(x + (size_t)row * HDIM + col4);
            *(float4*)(&xs[r][col4]) = v;
        }
        __syncthreads();

        float acc0 = 0.f, acc1 = 0.f, acc2 = 0.f, acc3 = 0.f;
        const float4* __restrict__ Wrow = (const float4*)(W + (size_t)j * HDIM);
        const int rb = rset << 2;
        #pragma unroll 8
        for (int k4 = 0; k4 < HDIM / 4; ++k4) {
            float4 w = Wrow[k4];
            float4 a = *(const float4*)(&xs[rb + 0][k4 << 2]);
            float4 b = *(const float4*)(&xs[rb + 1][k4 << 2]);
            float4 c = *(const float4*)(&xs[rb + 2][k4 << 2]);
            float4 d = *(const float4*)(&xs[rb + 3][k4 << 2]);
            acc0 += w.x * a.x + w.y * a.y + w.z * a.z + w.w * a.w;
            acc1 += w.x * b.x + w.y * b.y + w.z * b.z + w.w * b.w;
            acc2 += w.x * c.x + w.y * c.y + w.z * c.z + w.w * c.w;
            acc3 += w.x * d.x + w.y * d.y + w.z * d.z + w.w * d.w;
        }
        const int r0 = row0 + rb;
        if (r0 + 0 < n) g[(size_t)(r0 + 0) * HDIM + j] = acc0 * dinv[r0 + 0];
        if (r0 + 1 < n) g[(size_t)(r0 + 1) * HDIM + j] = acc1 * dinv[r0 + 1];
        if (r0 + 2 < n) g[(size_t)(r0 + 2) * HDIM + j] = acc2 * dinv[r0 + 2];
        if (r0 + 3 < n) g[(size_t)(r0 + 3) * HDIM + j] = acc3 * dinv[r0 + 3];
        __syncthreads();
    }
}

// ---------- 6. pull gather + fused epilogue ----------
__global__ __launch_bounds__(256) void gather_kernel(
    const int* __restrict__ row_ptr, const int* __restrict__ col,
    const float* __restrict__ g, const float* __restrict__ dinv,
    const float* __restrict__ bias, const float* __restrict__ prelu_a,
    float* __restrict__ out, int n) {
    const int wave = threadIdx.x >> 6;
    const int lane = threadIdx.x & 63;
    const int i = blockIdx.x * 4 + wave;
    if (i >= n) return;

    const int beg = row_ptr[i];
    const int end = row_ptr[i + 1];
    const float2* __restrict__ gp = (const float2*)g;

    float2 a0 = {0.f, 0.f}, a1 = {0.f, 0.f}, a2 = {0.f, 0.f}, a3 = {0.f, 0.f};
    int e = beg;
    for (; e + 4 <= end; e += 4) {
        int s0 = col[e], s1 = col[e + 1], s2 = col[e + 2], s3 = col[e + 3];
        float2 v0 = gp[(size_t)s0 * 64 + lane];
        float2 v1 = gp[(size_t)s1 * 64 + lane];
        float2 v2 = gp[(size_t)s2 * 64 + lane];
        float2 v3 = gp[(size_t)s3 * 64 + lane];
        a0.x += v0.x; a0.y += v0.y;
        a1.x += v1.x; a1.y += v1.y;
        a2.x += v2.x; a2.y += v2.y;
        a3.x += v3.x; a3.y += v3.y;
    }
    for (; e < end; ++e) {
        int s = col[e];
        float2 v = gp[(size_t)s * 64 + lane];
        a0.x += v.x; a0.y += v.y;
    }
    float accx = (a0.x + a1.x) + (a2.x + a3.x);
    float accy = (a0.y + a1.y) + (a2.y + a3.y);

    float2 self = gp[(size_t)i * 64 + lane];
    float di = dinv[i];
    float2 bb = *(const float2*)(bias + lane * 2);
    float aa = prelu_a[0];

    float vx = di * (accx + self.x) + bb.x;
    float vy = di * (accy + self.y) + bb.y;
    vx = vx >= 0.f ? vx : aa * vx;
    vy = vy >= 0.f ? vy : aa * vy;
    *(float2*)(out + (size_t)i * HDIM + lane * 2) = make_float2(vx, vy);
}

extern "C" void kernel_launch(void* const* d_in, const int* in_sizes, int n_in,
                              void* d_out, int out_size, void* d_ws, size_t ws_size,
                              hipStream_t stream) {
    const float* x  = (const float*)d_in[0];
    const int*   ei = (const int*)d_in[1];   // edge_index (2, E), int32
    const float* W  = (const float*)d_in[2];
    const float* b  = (const float*)d_in[3];
    const float* pa = (const float*)d_in[4];

    const int n = in_sizes[0] / HDIM;        // 100000
    const int E = in_sizes[1] / 2;           // 1600000

    float* out = (float*)d_out;

    // workspace layout:
    //   g       : n*128 floats
    //   dinv    : n floats
    //   cnt     : n ints
    //   row_ptr : n+1 ints
    //   ptr     : n ints
    //   bsum    : 1024 ints
    //   col     : E ints
    float* g       = (float*)d_ws;
    float* dinv    = g + (size_t)n * HDIM;
    int*   cnt     = (int*)(dinv + n);
    int*   row_ptr = cnt + n;
    int*   ptr     = row_ptr + (n + 1);
    int*   bsum    = ptr + n;
    int*   col     = bsum + 1024;

    const int nb = (n + 1023) / 1024;        // 98 blocks

    hipMemsetAsync(cnt, 0, (size_t)n * sizeof(int), stream);

    cnt_kernel<<<(E + 255) / 256, 256, 0, stream>>>(ei + E, E, cnt);
    dinv_kernel<<<(n + 255) / 256, 256, 0, stream>>>(cnt, dinv, n);
    scan1_kernel<<<nb, 1024, 0, stream>>>(cnt, bsum, n);
    scan2_kernel<<<1, 1024, 0, stream>>>(bsum, nb);
    scan3_kernel<<<nb, 1024, 0, stream>>>(cnt, bsum, row_ptr, ptr, n);
    fill_kernel<<<(E + 255) / 256, 256, 0, stream>>>(ei, E, ptr, col);
    gemm_kernel<<<1024, 256, 0, stream>>>(x, W, dinv, g, n);
    gather_kernel<<<(n + 3) / 4, 256, 0, stream>>>(row_ptr, col, g, dinv, b, pa, out, n);
}

// Round 4
// 454.094 us; speedup vs baseline: 6.7924x; 1.3312x over previous
//
#include <hip/hip_runtime.h>
#include <math.h>

#define HDIM 128

typedef __attribute__((ext_vector_type(8))) short short8;
typedef __attribute__((ext_vector_type(4))) float f32x4;

__device__ inline unsigned short bf16_hi(float f) {
    return (unsigned short)(__float_as_uint(f) >> 16);
}

// ---------- 1. in-degree histogram (dst occurrences, excl. self-loop) ----------
__global__ void cnt_kernel(const int* __restrict__ dst, int E, int* __restrict__ cnt) {
    int e = blockIdx.x * blockDim.x + threadIdx.x;
    if (e < E) atomicAdd(&cnt[dst[e]], 1);
}

// ---------- 2. dinv = 1/sqrt(cnt + 1) ----------
__global__ void dinv_kernel(const int* __restrict__ cnt, float* __restrict__ dinv, int n) {
    int i = blockIdx.x * blockDim.x + threadIdx.x;
    if (i < n) dinv[i] = rsqrtf((float)cnt[i] + 1.0f);
}

// ---------- 3a. per-block sums ----------
__global__ __launch_bounds__(1024) void scan1_kernel(
    const int* __restrict__ cnt, int* __restrict__ bsum, int n) {
    __shared__ int s[1024];
    const int t = threadIdx.x;
    int i = blockIdx.x * 1024 + t;
    s[t] = (i < n) ? cnt[i] : 0;
    __syncthreads();
    for (int off = 512; off > 0; off >>= 1) {
        if (t < off) s[t] += s[t + off];
        __syncthreads();
    }
    if (t == 0) bsum[blockIdx.x] = s[0];
}

// ---------- 3b. exclusive scan of block sums (nb <= 1024, single block) ----------
__global__ __launch_bounds__(1024) void scan2_kernel(int* __restrict__ bsum, int nb) {
    __shared__ int s[1024];
    const int t = threadIdx.x;
    int v = (t < nb) ? bsum[t] : 0;
    s[t] = v;
    __syncthreads();
    for (int off = 1; off < 1024; off <<= 1) {
        int u = (t >= off) ? s[t - off] : 0;
        __syncthreads();
        s[t] += u;
        __syncthreads();
    }
    if (t < nb) bsum[t] = s[t] - v;   // exclusive
}

// ---------- 3c. per-block exclusive scan + block offset -> row_ptr, ptr ----------
__global__ __launch_bounds__(1024) void scan3_kernel(
    const int* __restrict__ cnt, const int* __restrict__ bsum,
    int* __restrict__ row_ptr, int* __restrict__ ptr, int n) {
    __shared__ int s[1024];
    const int t = threadIdx.x;
    int i = blockIdx.x * 1024 + t;
    int v = (i < n) ? cnt[i] : 0;
    s[t] = v;
    __syncthreads();
    for (int off = 1; off < 1024; off <<= 1) {
        int u = (t >= off) ? s[t - off] : 0;
        __syncthreads();
        s[t] += u;
        __syncthreads();
    }
    int excl = s[t] - v + bsum[blockIdx.x];
    if (i < n) {
        row_ptr[i] = excl;
        ptr[i] = excl;
        if (i == n - 1) row_ptr[n] = excl + v;
    }
}

// ---------- 4. CSR fill: col[ptr[dst]++] = src ----------
__global__ void fill_kernel(const int* __restrict__ ei, int E,
                            int* __restrict__ ptr, int* __restrict__ col) {
    int e = blockIdx.x * blockDim.x + threadIdx.x;
    if (e >= E) return;
    int s = ei[e];        // src
    int d = ei[E + e];    // dst
    int pos = atomicAdd(&ptr[d], 1);
    col[pos] = s;
}

// ---------- 5. MFMA split-bf16 GEMM: g = (x @ W^T) * dinv ----------
// x:[n,128] fp32. W:[128,128] fp32 row-major (W[j][k]). 3-term split:
// x*W ~= xh*Wh + xl*Wh + xh*Wl (bf16 hi + residual lo), fp32 accumulate.
// Block = 256 thr (4 waves). Persistent blocks; W staged once into LDS as
// XOR-swizzled 16B chunks (chunk c of row j stored at c ^ (j&15)).
// Per group: 128 rows; wave w covers rows w*32..w*32+31 (2 M-tiles of 16).
// A-frags read from global fp32 and split hi/lo in registers.
__global__ __launch_bounds__(256) void mfma_gemm_kernel(
    const float* __restrict__ x, const float* __restrict__ W,
    const float* __restrict__ dinv, float* __restrict__ g, int n) {
    __shared__ uint4 Wh[2048];   // 128 rows x 16 chunks (8 bf16 each) = 32 KB
    __shared__ uint4 Wl[2048];   // 32 KB

    const int t = threadIdx.x;
    const int wave = t >> 6;
    const int lane = t & 63;
    const int q = lane >> 4;     // quad 0..3
    const int m = lane & 15;

    // ---- stage W (once) ----
    for (int idx = t; idx < 2048; idx += 256) {
        const int j = idx >> 4;
        const int c = idx & 15;
        const float4* wp = (const float4*)(W + (size_t)j * HDIM + c * 8);
        float4 va = wp[0], vb = wp[1];
        float vs[8] = {va.x, va.y, va.z, va.w, vb.x, vb.y, vb.z, vb.w};
        unsigned short h[8], l[8];
        #pragma unroll
        for (int k = 0; k < 8; ++k) {
            h[k] = bf16_hi(vs[k]);
            float hf = __uint_as_float((unsigned int)h[k] << 16);
            l[k] = bf16_hi(vs[k] - hf);
        }
        uint4 hch, lch;
        hch.x = (unsigned int)h[0] | ((unsigned int)h[1] << 16);
        hch.y = (unsigned int)h[2] | ((unsigned int)h[3] << 16);
        hch.z = (unsigned int)h[4] | ((unsigned int)h[5] << 16);
        hch.w = (unsigned int)h[6] | ((unsigned int)h[7] << 16);
        lch.x = (unsigned int)l[0] | ((unsigned int)l[1] << 16);
        lch.y = (unsigned int)l[2] | ((unsigned int)l[3] << 16);
        lch.z = (unsigned int)l[4] | ((unsigned int)l[5] << 16);
        lch.w = (unsigned int)l[6] | ((unsigned int)l[7] << 16);
        const int sidx = (j << 4) | (c ^ (j & 15));
        Wh[sidx] = hch;
        Wl[sidx] = lch;
    }
    __syncthreads();

    const int ngroups = (n + 127) >> 7;
    for (int grp = blockIdx.x; grp < ngroups; grp += gridDim.x) {
        const int rowbase = (grp << 7) + (wave << 5);

        f32x4 acc[2][8];
        #pragma unroll
        for (int mt = 0; mt < 2; ++mt)
            #pragma unroll
            for (int ct = 0; ct < 8; ++ct)
                acc[mt][ct] = (f32x4){0.f, 0.f, 0.f, 0.f};

        #pragma unroll
        for (int kk = 0; kk < 4; ++kk) {
            short8 ah[2], al[2];
            #pragma unroll
            for (int mt = 0; mt < 2; ++mt) {
                const int r = rowbase + (mt << 4) + m;
                float vs[8];
                if (r < n) {
                    const float4* xp = (const float4*)(x + (size_t)r * HDIM + (kk << 5) + (q << 3));
                    float4 va = xp[0], vb = xp[1];
                    vs[0] = va.x; vs[1] = va.y; vs[2] = va.z; vs[3] = va.w;
                    vs[4] = vb.x; vs[5] = vb.y; vs[6] = vb.z; vs[7] = vb.w;
                } else {
                    #pragma unroll
                    for (int k = 0; k < 8; ++k) vs[k] = 0.f;
                }
                #pragma unroll
                for (int k = 0; k < 8; ++k) {
                    unsigned short h = bf16_hi(vs[k]);
                    float hf = __uint_as_float((unsigned int)h << 16);
                    unsigned short lo = bf16_hi(vs[k] - hf);
                    ah[mt][k] = (short)h;
                    al[mt][k] = (short)lo;
                }
            }
            #pragma unroll
            for (int ct = 0; ct < 8; ++ct) {
                const int nn = (ct << 4) + m;
                const int sidx = (nn << 4) | (((kk << 2) + q) ^ m);
                short8 bh = *(const short8*)&Wh[sidx];
                short8 bl = *(const short8*)&Wl[sidx];
                #pragma unroll
                for (int mt = 0; mt < 2; ++mt) {
                    acc[mt][ct] = __builtin_amdgcn_mfma_f32_16x16x32_bf16(ah[mt], bh, acc[mt][ct], 0, 0, 0);
                    acc[mt][ct] = __builtin_amdgcn_mfma_f32_16x16x32_bf16(al[mt], bh, acc[mt][ct], 0, 0, 0);
                    acc[mt][ct] = __builtin_amdgcn_mfma_f32_16x16x32_bf16(ah[mt], bl, acc[mt][ct], 0, 0, 0);
                }
            }
        }

        // ---- scale by dinv[row] and store ----
        #pragma unroll
        for (int mt = 0; mt < 2; ++mt) {
            #pragma unroll
            for (int rr = 0; rr < 4; ++rr) {
                const int grow = rowbase + (mt << 4) + (q << 2) + rr;
                if (grow < n) {
                    const float di = dinv[grow];
                    float* gp = g + (size_t)grow * HDIM + m;
                    #pragma unroll
                    for (int ct = 0; ct < 8; ++ct)
                        gp[ct << 4] = acc[mt][ct][rr] * di;
                }
            }
        }
    }
}

// ---------- 6. pull gather + fused epilogue ----------
__global__ __launch_bounds__(256) void gather_kernel(
    const int* __restrict__ row_ptr, const int* __restrict__ col,
    const float* __restrict__ g, const float* __restrict__ dinv,
    const float* __restrict__ bias, const float* __restrict__ prelu_a,
    float* __restrict__ out, int n) {
    const int wave = threadIdx.x >> 6;
    const int lane = threadIdx.x & 63;
    const int i = blockIdx.x * 4 + wave;
    if (i >= n) return;

    const int beg = row_ptr[i];
    const int end = row_ptr[i + 1];
    const float2* __restrict__ gp = (const float2*)g;

    float2 a0 = {0.f, 0.f}, a1 = {0.f, 0.f}, a2 = {0.f, 0.f}, a3 = {0.f, 0.f};
    int e = beg;
    for (; e + 4 <= end; e += 4) {
        int s0 = col[e], s1 = col[e + 1], s2 = col[e + 2], s3 = col[e + 3];
        float2 v0 = gp[(size_t)s0 * 64 + lane];
        float2 v1 = gp[(size_t)s1 * 64 + lane];
        float2 v2 = gp[(size_t)s2 * 64 + lane];
        float2 v3 = gp[(size_t)s3 * 64 + lane];
        a0.x += v0.x; a0.y += v0.y;
        a1.x += v1.x; a1.y += v1.y;
        a2.x += v2.x; a2.y += v2.y;
        a3.x += v3.x; a3.y += v3.y;
    }
    for (; e < end; ++e) {
        int s = col[e];
        float2 v = gp[(size_t)s * 64 + lane];
        a0.x += v.x; a0.y += v.y;
    }
    float accx = (a0.x + a1.x) + (a2.x + a3.x);
    float accy = (a0.y + a1.y) + (a2.y + a3.y);

    float2 self = gp[(size_t)i * 64 + lane];
    float di = dinv[i];
    float2 bb = *(const float2*)(bias + lane * 2);
    float aa = prelu_a[0];

    float vx = di * (accx + self.x) + bb.x;
    float vy = di * (accy + self.y) + bb.y;
    vx = vx >= 0.f ? vx : aa * vx;
    vy = vy >= 0.f ? vy : aa * vy;
    *(float2*)(out + (size_t)i * HDIM + lane * 2) = make_float2(vx, vy);
}

extern "C" void kernel_launch(void* const* d_in, const int* in_sizes, int n_in,
                              void* d_out, int out_size, void* d_ws, size_t ws_size,
                              hipStream_t stream) {
    const float* x  = (const float*)d_in[0];
    const int*   ei = (const int*)d_in[1];   // edge_index (2, E), int32
    const float* W  = (const float*)d_in[2];
    const float* b  = (const float*)d_in[3];
    const float* pa = (const float*)d_in[4];

    const int n = in_sizes[0] / HDIM;        // 100000
    const int E = in_sizes[1] / 2;           // 1600000

    float* out = (float*)d_out;

    // workspace layout:
    //   g       : n*128 floats
    //   dinv    : n floats
    //   cnt     : n ints
    //   row_ptr : n+1 ints
    //   ptr     : n ints
    //   bsum    : 1024 ints
    //   col     : E ints
    float* g       = (float*)d_ws;
    float* dinv    = g + (size_t)n * HDIM;
    int*   cnt     = (int*)(dinv + n);
    int*   row_ptr = cnt + n;
    int*   ptr     = row_ptr + (n + 1);
    int*   bsum    = ptr + n;
    int*   col     = bsum + 1024;

    const int nb = (n + 1023) / 1024;        // 98 blocks

    hipMemsetAsync(cnt, 0, (size_t)n * sizeof(int), stream);

    cnt_kernel<<<(E + 255) / 256, 256, 0, stream>>>(ei + E, E, cnt);
    dinv_kernel<<<(n + 255) / 256, 256, 0, stream>>>(cnt, dinv, n);
    scan1_kernel<<<nb, 1024, 0, stream>>>(cnt, bsum, n);
    scan2_kernel<<<1, 1024, 0, stream>>>(bsum, nb);
    scan3_kernel<<<nb, 1024, 0, stream>>>(cnt, bsum, row_ptr, ptr, n);
    fill_kernel<<<(E + 255) / 256, 256, 0, stream>>>(ei, E, ptr, col);
    mfma_gemm_kernel<<<512, 256, 0, stream>>>(x, W, dinv, g, n);
    gather_kernel<<<(n + 3) / 4, 256, 0, stream>>>(row_ptr, col, g, dinv, b, pa, out, n);
}

// Round 5
// 343.204 us; speedup vs baseline: 8.9871x; 1.3231x over previous
//
#include <hip/hip_runtime.h>
#include <math.h>

#define HDIM 128
#define BSH 9                 // bucket shift: 512 nodes per bucket
#define CH 4096               // edges per binB chunk

typedef __attribute__((ext_vector_type(8))) short short8;
typedef __attribute__((ext_vector_type(4))) float f32x4;

__device__ inline unsigned short bf16_hi(float f) {
    return (unsigned short)(__float_as_uint(f) >> 16);
}
__device__ inline unsigned short bf16_rn(float f) {
    unsigned int u = __float_as_uint(f);
    return (unsigned short)((u + 0x7FFF + ((u >> 16) & 1)) >> 16);
}
__device__ inline float bf2f(unsigned short h) {
    return __uint_as_float((unsigned int)h << 16);
}

// ---------- 1. in-degree histogram (dst occurrences, excl. self-loop) ----------
__global__ void cnt_kernel(const int* __restrict__ dst, int E, int* __restrict__ cnt) {
    int e = blockIdx.x * blockDim.x + threadIdx.x;
    if (e < E) atomicAdd(&cnt[dst[e]], 1);
}

// ---------- 2a. per-block sums (+ fused dinv = rsqrt(cnt+1)) ----------
__global__ __launch_bounds__(1024) void scan1_kernel(
    const int* __restrict__ cnt, int* __restrict__ bsum,
    float* __restrict__ dinv, int n) {
    __shared__ int s[1024];
    const int t = threadIdx.x;
    int i = blockIdx.x * 1024 + t;
    int v = (i < n) ? cnt[i] : 0;
    s[t] = v;
    if (i < n) dinv[i] = rsqrtf((float)v + 1.0f);
    __syncthreads();
    for (int off = 512; off > 0; off >>= 1) {
        if (t < off) s[t] += s[t + off];
        __syncthreads();
    }
    if (t == 0) bsum[blockIdx.x] = s[0];
}

// ---------- 2b. exclusive scan of block sums (nb <= 1024, single block) ----------
__global__ __launch_bounds__(1024) void scan2_kernel(int* __restrict__ bsum, int nb) {
    __shared__ int s[1024];
    const int t = threadIdx.x;
    int v = (t < nb) ? bsum[t] : 0;
    s[t] = v;
    __syncthreads();
    for (int off = 1; off < 1024; off <<= 1) {
        int u = (t >= off) ? s[t - off] : 0;
        __syncthreads();
        s[t] += u;
        __syncthreads();
    }
    if (t < nb) bsum[t] = s[t] - v;   // exclusive
}

// ---------- 2c. per-block exclusive scan + offset -> row_ptr, ptr, bcur ----------
__global__ __launch_bounds__(1024) void scan3_kernel(
    const int* __restrict__ cnt, const int* __restrict__ bsum,
    int* __restrict__ row_ptr, int* __restrict__ ptr,
    int* __restrict__ bcur, int n) {
    __shared__ int s[1024];
    const int t = threadIdx.x;
    int i = blockIdx.x * 1024 + t;
    int v = (i < n) ? cnt[i] : 0;
    s[t] = v;
    __syncthreads();
    for (int off = 1; off < 1024; off <<= 1) {
        int u = (t >= off) ? s[t - off] : 0;
        __syncthreads();
        s[t] += u;
        __syncthreads();
    }
    int excl = s[t] - v + bsum[blockIdx.x];
    if (i < n) {
        row_ptr[i] = excl;
        ptr[i] = excl;
        if ((i & ((1 << BSH) - 1)) == 0) bcur[i >> BSH] = excl;  // bucket cursor init
        if (i == n - 1) row_ptr[n] = excl + v;
    }
}

// ---------- 3a. bin edges into bucket-major eb[] (contiguous per-chunk runs) ----------
__global__ __launch_bounds__(256) void binB_kernel(
    const int* __restrict__ ei, int E,
    int* __restrict__ bcur, int2* __restrict__ eb) {
    __shared__ int hist[256], base[256], cur[256];
    const int t = threadIdx.x;
    const int c0 = blockIdx.x * CH;
    hist[t] = 0;
    __syncthreads();

    int sv[CH / 256], dv[CH / 256];
    #pragma unroll
    for (int k = 0; k < CH / 256; ++k) {
        int e = c0 + t + (k << 8);
        if (e < E) {
            sv[k] = ei[e];
            dv[k] = ei[E + e];
            atomicAdd(&hist[dv[k] >> BSH], 1);
        } else {
            dv[k] = -1;
        }
    }
    __syncthreads();
    if (hist[t] > 0) base[t] = atomicAdd(&bcur[t], hist[t]);
    cur[t] = 0;
    __syncthreads();
    #pragma unroll
    for (int k = 0; k < CH / 256; ++k) {
        if (dv[k] >= 0) {
            int bkt = dv[k] >> BSH;
            int o = atomicAdd(&cur[bkt], 1);
            eb[(size_t)base[bkt] + o] = make_int2(sv[k], dv[k]);
        }
    }
}

// ---------- 3b. per-bucket CSR fill (all traffic bucket-local) ----------
__global__ __launch_bounds__(256) void binC_kernel(
    const int2* __restrict__ eb, const int* __restrict__ row_ptr,
    int* __restrict__ ptr, int* __restrict__ col, int n) {
    const int b = blockIdx.x;
    const int node0 = b << BSH;
    int node1 = node0 + (1 << BSH);
    if (node1 > n) node1 = n;
    const int e0 = row_ptr[node0];
    const int e1 = row_ptr[node1];
    for (int e = e0 + threadIdx.x; e < e1; e += 256) {
        int2 p = eb[e];
        int pos = atomicAdd(&ptr[p.y], 1);
        col[pos] = p.x;
    }
}

// ---------- 4. MFMA split-bf16 GEMM: gb = bf16(x @ W^T) ----------
// 3-term split: x*W ~= xh*Wh + xl*Wh + xh*Wl, fp32 accumulate, bf16 store.
__global__ __launch_bounds__(256) void mfma_gemm_kernel(
    const float* __restrict__ x, const float* __restrict__ W,
    unsigned short* __restrict__ gb, int n) {
    __shared__ uint4 Wh[2048];   // 128 rows x 16 chunks (8 bf16 each) = 32 KB
    __shared__ uint4 Wl[2048];   // 32 KB

    const int t = threadIdx.x;
    const int wave = t >> 6;
    const int lane = t & 63;
    const int q = lane >> 4;     // quad 0..3
    const int m = lane & 15;

    // ---- stage W (once) ----
    for (int idx = t; idx < 2048; idx += 256) {
        const int j = idx >> 4;
        const int c = idx & 15;
        const float4* wp = (const float4*)(W + (size_t)j * HDIM + c * 8);
        float4 va = wp[0], vb = wp[1];
        float vs[8] = {va.x, va.y, va.z, va.w, vb.x, vb.y, vb.z, vb.w};
        unsigned short h[8], l[8];
        #pragma unroll
        for (int k = 0; k < 8; ++k) {
            h[k] = bf16_hi(vs[k]);
            float hf = __uint_as_float((unsigned int)h[k] << 16);
            l[k] = bf16_hi(vs[k] - hf);
        }
        uint4 hch, lch;
        hch.x = (unsigned int)h[0] | ((unsigned int)h[1] << 16);
        hch.y = (unsigned int)h[2] | ((unsigned int)h[3] << 16);
        hch.z = (unsigned int)h[4] | ((unsigned int)h[5] << 16);
        hch.w = (unsigned int)h[6] | ((unsigned int)h[7] << 16);
        lch.x = (unsigned int)l[0] | ((unsigned int)l[1] << 16);
        lch.y = (unsigned int)l[2] | ((unsigned int)l[3] << 16);
        lch.z = (unsigned int)l[4] | ((unsigned int)l[5] << 16);
        lch.w = (unsigned int)l[6] | ((unsigned int)l[7] << 16);
        const int sidx = (j << 4) | (c ^ (j & 15));
        Wh[sidx] = hch;
        Wl[sidx] = lch;
    }
    __syncthreads();

    const int ngroups = (n + 127) >> 7;
    for (int grp = blockIdx.x; grp < ngroups; grp += gridDim.x) {
        const int rowbase = (grp << 7) + (wave << 5);

        f32x4 acc[2][8];
        #pragma unroll
        for (int mt = 0; mt < 2; ++mt)
            #pragma unroll
            for (int ct = 0; ct < 8; ++ct)
                acc[mt][ct] = (f32x4){0.f, 0.f, 0.f, 0.f};

        #pragma unroll
        for (int kk = 0; kk < 4; ++kk) {
            short8 ah[2], al[2];
            #pragma unroll
            for (int mt = 0; mt < 2; ++mt) {
                const int r = rowbase + (mt << 4) + m;
                float vs[8];
                if (r < n) {
                    const float4* xp = (const float4*)(x + (size_t)r * HDIM + (kk << 5) + (q << 3));
                    float4 va = xp[0], vb = xp[1];
                    vs[0] = va.x; vs[1] = va.y; vs[2] = va.z; vs[3] = va.w;
                    vs[4] = vb.x; vs[5] = vb.y; vs[6] = vb.z; vs[7] = vb.w;
                } else {
                    #pragma unroll
                    for (int k = 0; k < 8; ++k) vs[k] = 0.f;
                }
                #pragma unroll
                for (int k = 0; k < 8; ++k) {
                    unsigned short h = bf16_hi(vs[k]);
                    float hf = __uint_as_float((unsigned int)h << 16);
                    unsigned short lo = bf16_hi(vs[k] - hf);
                    ah[mt][k] = (short)h;
                    al[mt][k] = (short)lo;
                }
            }
            #pragma unroll
            for (int ct = 0; ct < 8; ++ct) {
                const int nn = (ct << 4) + m;
                const int sidx = (nn << 4) | (((kk << 2) + q) ^ m);
                short8 bh = *(const short8*)&Wh[sidx];
                short8 bl = *(const short8*)&Wl[sidx];
                #pragma unroll
                for (int mt = 0; mt < 2; ++mt) {
                    acc[mt][ct] = __builtin_amdgcn_mfma_f32_16x16x32_bf16(ah[mt], bh, acc[mt][ct], 0, 0, 0);
                    acc[mt][ct] = __builtin_amdgcn_mfma_f32_16x16x32_bf16(al[mt], bh, acc[mt][ct], 0, 0, 0);
                    acc[mt][ct] = __builtin_amdgcn_mfma_f32_16x16x32_bf16(ah[mt], bl, acc[mt][ct], 0, 0, 0);
                }
            }
        }

        // ---- store bf16 (no dinv here; applied in gather) ----
        #pragma unroll
        for (int mt = 0; mt < 2; ++mt) {
            #pragma unroll
            for (int rr = 0; rr < 4; ++rr) {
                const int grow = rowbase + (mt << 4) + (q << 2) + rr;
                if (grow < n) {
                    unsigned short* gp = gb + (size_t)grow * HDIM + m;
                    #pragma unroll
                    for (int ct = 0; ct < 8; ++ct)
                        gp[ct << 4] = bf16_rn(acc[mt][ct][rr]);
                }
            }
        }
    }
}

// ---------- 5. pull gather (bf16 g) + fused epilogue ----------
// One wave per node; half-wave (32 lanes) per edge, lane covers 4 cols (8 B load).
// out = dinv_i * ( sum_e dinv_src * h_src  +  dinv_i * h_i ) + b, then PReLU.
__global__ __launch_bounds__(256) void gather_kernel(
    const int* __restrict__ row_ptr, const int* __restrict__ col,
    const unsigned short* __restrict__ gb, const float* __restrict__ dinv,
    const float* __restrict__ bias, const float* __restrict__ prelu_a,
    float* __restrict__ out, int n) {
    const int wv = threadIdx.x >> 6;
    const int lane = threadIdx.x & 63;
    const int half = lane >> 5;
    const int le = lane & 31;          // cols le*4 .. le*4+3
    const int i = blockIdx.x * 4 + wv;
    if (i >= n) return;

    const int beg = row_ptr[i];
    const int end = row_ptr[i + 1];

    float a0 = 0.f, a1 = 0.f, a2 = 0.f, a3 = 0.f;
    int e = beg + half;
    for (; e + 2 < end; e += 4) {       // 2 edges per half-wave per iter
        int s0 = col[e], s1 = col[e + 2];
        float d0 = dinv[s0], d1 = dinv[s1];
        ushort4 u0 = *(const ushort4*)(gb + (size_t)s0 * HDIM + (le << 2));
        ushort4 u1 = *(const ushort4*)(gb + (size_t)s1 * HDIM + (le << 2));
        a0 += d0 * bf2f(u0.x) + d1 * bf2f(u1.x);
        a1 += d0 * bf2f(u0.y) + d1 * bf2f(u1.y);
        a2 += d0 * bf2f(u0.z) + d1 * bf2f(u1.z);
        a3 += d0 * bf2f(u0.w) + d1 * bf2f(u1.w);
    }
    if (e < end) {
        int s = col[e];
        float d = dinv[s];
        ushort4 u = *(const ushort4*)(gb + (size_t)s * HDIM + (le << 2));
        a0 += d * bf2f(u.x);
        a1 += d * bf2f(u.y);
        a2 += d * bf2f(u.z);
        a3 += d * bf2f(u.w);
    }
    // combine the two half-waves
    a0 += __shfl_down(a0, 32);
    a1 += __shfl_down(a1, 32);
    a2 += __shfl_down(a2, 32);
    a3 += __shfl_down(a3, 32);

    if (half == 0) {
        ushort4 us = *(const ushort4*)(gb + (size_t)i * HDIM + (le << 2));
        float di = dinv[i];
        float4 bb = *(const float4*)(bias + (le << 2));
        float aa = prelu_a[0];
        float v0 = di * (a0 + di * bf2f(us.x)) + bb.x;
        float v1 = di * (a1 + di * bf2f(us.y)) + bb.y;
        float v2 = di * (a2 + di * bf2f(us.z)) + bb.z;
        float v3 = di * (a3 + di * bf2f(us.w)) + bb.w;
        v0 = v0 >= 0.f ? v0 : aa * v0;
        v1 = v1 >= 0.f ? v1 : aa * v1;
        v2 = v2 >= 0.f ? v2 : aa * v2;
        v3 = v3 >= 0.f ? v3 : aa * v3;
        *(float4*)(out + (size_t)i * HDIM + (le << 2)) = make_float4(v0, v1, v2, v3);
    }
}

extern "C" void kernel_launch(void* const* d_in, const int* in_sizes, int n_in,
                              void* d_out, int out_size, void* d_ws, size_t ws_size,
                              hipStream_t stream) {
    const float* x  = (const float*)d_in[0];
    const int*   ei = (const int*)d_in[1];   // edge_index (2, E), int32
    const float* W  = (const float*)d_in[2];
    const float* b  = (const float*)d_in[3];
    const float* pa = (const float*)d_in[4];

    const int n = in_sizes[0] / HDIM;        // 100000
    const int E = in_sizes[1] / 2;           // 1600000
    const int NB = (n + (1 << BSH) - 1) >> BSH;   // 196 buckets (<=256)

    float* out = (float*)d_out;

    // workspace layout (8B-aligned first):
    //   eb      : E int2          (12.8 MB)
    //   gb      : n*128 ushort    (25.6 MB)
    //   dinv    : n floats
    //   cnt     : n ints
    //   row_ptr : n+1 ints
    //   ptr     : n ints
    //   bcur    : 256 ints
    //   bsum    : 1024 ints
    //   col     : E ints
    int2*           eb      = (int2*)d_ws;
    unsigned short* gb      = (unsigned short*)(eb + (size_t)E);
    float*          dinv    = (float*)(gb + (size_t)n * HDIM);
    int*            cnt     = (int*)(dinv + n);
    int*            row_ptr = cnt + n;
    int*            ptr     = row_ptr + (n + 1);
    int*            bcur    = ptr + n;
    int*            bsum    = bcur + 256;
    int*            col     = bsum + 1024;

    const int nb = (n + 1023) / 1024;        // 98 scan blocks

    hipMemsetAsync(cnt, 0, (size_t)n * sizeof(int), stream);

    cnt_kernel<<<(E + 255) / 256, 256, 0, stream>>>(ei + E, E, cnt);
    scan1_kernel<<<nb, 1024, 0, stream>>>(cnt, bsum, dinv, n);
    scan2_kernel<<<1, 1024, 0, stream>>>(bsum, nb);
    scan3_kernel<<<nb, 1024, 0, stream>>>(cnt, bsum, row_ptr, ptr, bcur, n);
    binB_kernel<<<(E + CH - 1) / CH, 256, 0, stream>>>(ei, E, bcur, eb);
    mfma_gemm_kernel<<<512, 256, 0, stream>>>(x, W, gb, n);
    binC_kernel<<<NB, 256, 0, stream>>>(eb, row_ptr, ptr, col, n);
    gather_kernel<<<(n + 3) / 4, 256, 0, stream>>>(row_ptr, col, gb, dinv, b, pa, out, n);
}